// Round 1
// baseline (316.305 us; speedup 1.0000x reference)
//
#include <hip/hip_runtime.h>
#include <hip/hip_bf16.h>
#include <stdint.h>

#define DM 1024
#define NPAT 8
#define BM 128
#define BN 128
#define BK 32

typedef __bf16 bf16x8_t __attribute__((ext_vector_type(8)));
typedef float f32x4_t __attribute__((ext_vector_type(4)));
typedef unsigned short u16;

typedef const __attribute__((address_space(1))) void* gas_ptr;
typedef __attribute__((address_space(3))) void* las_ptr;

__device__ __forceinline__ u16 f2bf(float x) {
  uint32_t u = __float_as_uint(x);
  uint32_t r = (u + 0x7FFFu + ((u >> 16) & 1u)) >> 16;  // RNE
  return (u16)r;
}

// ---------------- K0: proj_w f32 -> bf16 ----------------
__global__ __launch_bounds__(256) void k0_cvt_w(const float* __restrict__ w,
                                                u16* __restrict__ wb) {
  int i = blockIdx.x * 256 + threadIdx.x;  // grid sized exactly: DM*DM/4 elems
  float4 v = ((const float4*)w)[i];
  ushort4 o;
  o.x = f2bf(v.x); o.y = f2bf(v.y); o.z = f2bf(v.z); o.w = f2bf(v.w);
  ((ushort4*)wb)[i] = o;
}

// ---------------- K1: hopfield read + residual + cast ----------------
// A[m, d] = h[m,d] + sum_p softmax_p(h[m,:].pat[p,:]) * pat[p,d]   (bf16 out)
__global__ __launch_bounds__(256) void k1_hopfield(const float* __restrict__ h,
                                                   const float* __restrict__ pat,
                                                   u16* __restrict__ A, int M) {
  __shared__ float patL[NPAT * DM];  // 32 KiB
  const int tid = threadIdx.x;
  {
    const float4* p4 = (const float4*)pat;
    float4* l4 = (float4*)patL;
#pragma unroll
    for (int i = 0; i < (NPAT * DM / 4) / 256; ++i)
      l4[i * 256 + tid] = p4[i * 256 + tid];
  }
  __syncthreads();

  const int lane = tid & 63;
  const int wid = (blockIdx.x << 2) | (tid >> 6);
  const int nw = gridDim.x << 2;
  const float4* h4 = (const float4*)h;
  const float4* pl4 = (const float4*)patL;
  ushort4* A4 = (ushort4*)A;

  for (int rp = wid; rp < (M >> 1); rp += nw) {
    const size_t r0 = (size_t)rp << 1;
    float4 hv0[4], hv1[4];
#pragma unroll
    for (int j = 0; j < 4; ++j) {
      hv0[j] = h4[r0 * 256 + j * 64 + lane];
      hv1[j] = h4[(r0 + 1) * 256 + j * 64 + lane];
    }
    float d0[NPAT], d1[NPAT];
#pragma unroll
    for (int p = 0; p < NPAT; ++p) {
      float a = 0.f, b = 0.f;
#pragma unroll
      for (int j = 0; j < 4; ++j) {
        float4 pv = pl4[p * 256 + j * 64 + lane];
        a = fmaf(hv0[j].x, pv.x, a); a = fmaf(hv0[j].y, pv.y, a);
        a = fmaf(hv0[j].z, pv.z, a); a = fmaf(hv0[j].w, pv.w, a);
        b = fmaf(hv1[j].x, pv.x, b); b = fmaf(hv1[j].y, pv.y, b);
        b = fmaf(hv1[j].z, pv.z, b); b = fmaf(hv1[j].w, pv.w, b);
      }
      d0[p] = a; d1[p] = b;
    }
#pragma unroll
    for (int p = 0; p < NPAT; ++p) {
#pragma unroll
      for (int o = 32; o > 0; o >>= 1) {
        d0[p] += __shfl_xor(d0[p], o);
        d1[p] += __shfl_xor(d1[p], o);
      }
    }
    // softmax over 8 (beta = 1)
    float m0 = d0[0], m1 = d1[0];
#pragma unroll
    for (int p = 1; p < NPAT; ++p) { m0 = fmaxf(m0, d0[p]); m1 = fmaxf(m1, d1[p]); }
    float s0 = 0.f, s1 = 0.f;
#pragma unroll
    for (int p = 0; p < NPAT; ++p) {
      d0[p] = __expf(d0[p] - m0); s0 += d0[p];
      d1[p] = __expf(d1[p] - m1); s1 += d1[p];
    }
    const float i0 = 1.f / s0, i1 = 1.f / s1;
#pragma unroll
    for (int p = 0; p < NPAT; ++p) { d0[p] *= i0; d1[p] *= i1; }

#pragma unroll
    for (int j = 0; j < 4; ++j) {
      float4 a0 = hv0[j], a1 = hv1[j];
#pragma unroll
      for (int p = 0; p < NPAT; ++p) {
        float4 pv = pl4[p * 256 + j * 64 + lane];
        a0.x = fmaf(d0[p], pv.x, a0.x); a0.y = fmaf(d0[p], pv.y, a0.y);
        a0.z = fmaf(d0[p], pv.z, a0.z); a0.w = fmaf(d0[p], pv.w, a0.w);
        a1.x = fmaf(d1[p], pv.x, a1.x); a1.y = fmaf(d1[p], pv.y, a1.y);
        a1.z = fmaf(d1[p], pv.z, a1.z); a1.w = fmaf(d1[p], pv.w, a1.w);
      }
      ushort4 o0, o1;
      o0.x = f2bf(a0.x); o0.y = f2bf(a0.y); o0.z = f2bf(a0.z); o0.w = f2bf(a0.w);
      o1.x = f2bf(a1.x); o1.y = f2bf(a1.y); o1.z = f2bf(a1.z); o1.w = f2bf(a1.w);
      A4[r0 * 256 + j * 64 + lane] = o0;
      A4[(r0 + 1) * 256 + j * 64 + lane] = o1;
    }
  }
}

// ---------------- K2: C[M,1024] = A_bf16 @ Wb^T + bias (f32 out) ----------------
// m97-structure: 128x128 tile, BK=32, 4 waves (2x2), global_load_lds width-16.
__global__ __launch_bounds__(256) void k2_gemm(const u16* __restrict__ A,
                                               const u16* __restrict__ B,
                                               const float* __restrict__ bias,
                                               float* __restrict__ C, int M) {
  __shared__ u16 Als[BM * BK];  // 8 KiB, linear [128][32]
  __shared__ u16 Bls[BN * BK];  // 8 KiB
  const int tid = threadIdx.x;
  const int lane = tid & 63;
  const int wave = tid >> 6;
  const int tn = blockIdx.x & 7;         // 1024/BN = 8
  const int tm = blockIdx.x >> 3;

  const u16* Ab = A + (size_t)tm * BM * DM;
  const u16* Bb = B + (size_t)tn * BN * DM;

  // staging chunks: c covers LDS bytes [c*16, c*16+16) == row c>>2, bf16 cols (c&3)*8..+8
  const int c0 = tid, c1 = tid + 256;
  const int goff0 = (c0 >> 2) * DM + (c0 & 3) * 8;
  const int goff1 = (c1 >> 2) * DM + (c1 & 3) * 8;
  char* AlsB = (char*)Als;
  char* BlsB = (char*)Bls;
  const uint32_t l0 = (uint32_t)c0 * 16;
  const uint32_t l1 = (uint32_t)c1 * 16;

  const int wr = wave >> 1, wc = wave & 1;
  const int r16 = lane & 15, kg = lane >> 4;
  uint32_t aF[4], bF[4];
#pragma unroll
  for (int m = 0; m < 4; ++m) aF[m] = (uint32_t)((wr * 64 + m * 16 + r16) * BK + kg * 8) * 2;
#pragma unroll
  for (int n = 0; n < 4; ++n) bF[n] = (uint32_t)((wc * 64 + n * 16 + r16) * BK + kg * 8) * 2;

  f32x4_t acc[4][4] = {};

  for (int kt = 0; kt < DM / BK; ++kt) {
    const int ko = kt * BK;
    __builtin_amdgcn_global_load_lds((gas_ptr)(Ab + goff0 + ko), (las_ptr)(AlsB + l0), 16, 0, 0);
    __builtin_amdgcn_global_load_lds((gas_ptr)(Ab + goff1 + ko), (las_ptr)(AlsB + l1), 16, 0, 0);
    __builtin_amdgcn_global_load_lds((gas_ptr)(Bb + goff0 + ko), (las_ptr)(BlsB + l0), 16, 0, 0);
    __builtin_amdgcn_global_load_lds((gas_ptr)(Bb + goff1 + ko), (las_ptr)(BlsB + l1), 16, 0, 0);
    __syncthreads();  // drains vmcnt before any wave reads LDS

    bf16x8_t av[4], bv[4];
#pragma unroll
    for (int m = 0; m < 4; ++m) av[m] = *(const bf16x8_t*)(AlsB + aF[m]);
#pragma unroll
    for (int n = 0; n < 4; ++n) bv[n] = *(const bf16x8_t*)(BlsB + bF[n]);
#pragma unroll
    for (int m = 0; m < 4; ++m)
#pragma unroll
      for (int n = 0; n < 4; ++n)
        acc[m][n] = __builtin_amdgcn_mfma_f32_16x16x32_bf16(av[m], bv[n], acc[m][n], 0, 0, 0);
    __syncthreads();  // compute done before next stage overwrites
  }

  // epilogue: C/D layout col = lane&15, row = (lane>>4)*4 + reg  [m89-verified]
  const int colB = tn * BN + wc * 64 + r16;
  float bvv[4];
#pragma unroll
  for (int n = 0; n < 4; ++n) bvv[n] = bias[colB + n * 16];
  const int rowB = tm * BM + wr * 64 + kg * 4;
#pragma unroll
  for (int m = 0; m < 4; ++m) {
#pragma unroll
    for (int r = 0; r < 4; ++r) {
      float* cp = C + (size_t)(rowB + m * 16 + r) * DM + colB;
#pragma unroll
      for (int n = 0; n < 4; ++n) cp[n * 16] = acc[m][n][r] + bvv[n];
    }
  }
}

extern "C" void kernel_launch(void* const* d_in, const int* in_sizes, int n_in,
                              void* d_out, int out_size, void* d_ws, size_t ws_size,
                              hipStream_t stream) {
  const float* h = (const float*)d_in[0];
  const float* pat = (const float*)d_in[1];
  const float* w = (const float*)d_in[2];
  const float* b = (const float*)d_in[3];
  float* out = (float*)d_out;
  const int M = in_sizes[0] / DM;  // 65536

  u16* Wb = (u16*)d_ws;                       // DM*DM bf16 = 2 MiB
  u16* Abf = (u16*)d_ws + (size_t)DM * DM;    // M*DM bf16 = 128 MiB

  k0_cvt_w<<<DM * DM / 4 / 256, 256, 0, stream>>>(w, Wb);
  k1_hopfield<<<2048, 256, 0, stream>>>(h, pat, Abf, M);
  k2_gemm<<<(M / BM) * (DM / BN), 256, 0, stream>>>(Abf, Wb, b, out, M);
}

// Round 2
// 252.339 us; speedup vs baseline: 1.2535x; 1.2535x over previous
//
#include <hip/hip_runtime.h>
#include <hip/hip_bf16.h>
#include <stdint.h>

#define DM 1024
#define NPAT 8
#define NKT 16  // K-tiles of 64: 1024/64
#define LDS_A 0
#define LDS_B 65536

typedef __bf16 bf16x8_t __attribute__((ext_vector_type(8)));
typedef float f32x4_t __attribute__((ext_vector_type(4)));
typedef unsigned short u16;

typedef const __attribute__((address_space(1))) void* gas_ptr;
typedef __attribute__((address_space(3))) void* las_ptr;

__device__ __forceinline__ u16 f2bf(float x) {
  uint32_t u = __float_as_uint(x);
  uint32_t r = (u + 0x7FFFu + ((u >> 16) & 1u)) >> 16;  // RNE
  return (u16)r;
}

// ---------------- K0: proj_w f32 -> bf16 ----------------
__global__ __launch_bounds__(256) void k0_cvt_w(const float* __restrict__ w,
                                                u16* __restrict__ wb) {
  int i = blockIdx.x * 256 + threadIdx.x;
  float4 v = ((const float4*)w)[i];
  ushort4 o;
  o.x = f2bf(v.x); o.y = f2bf(v.y); o.z = f2bf(v.z); o.w = f2bf(v.w);
  ((ushort4*)wb)[i] = o;
}

// ---------------- K1: hopfield read + residual + cast (unchanged, ~80us) ----
__global__ __launch_bounds__(256) void k1_hopfield(const float* __restrict__ h,
                                                   const float* __restrict__ pat,
                                                   u16* __restrict__ A, int M) {
  __shared__ float patL[NPAT * DM];
  const int tid = threadIdx.x;
  {
    const float4* p4 = (const float4*)pat;
    float4* l4 = (float4*)patL;
#pragma unroll
    for (int i = 0; i < (NPAT * DM / 4) / 256; ++i)
      l4[i * 256 + tid] = p4[i * 256 + tid];
  }
  __syncthreads();

  const int lane = tid & 63;
  const int wid = (blockIdx.x << 2) | (tid >> 6);
  const int nw = gridDim.x << 2;
  const float4* h4 = (const float4*)h;
  const float4* pl4 = (const float4*)patL;
  ushort4* A4 = (ushort4*)A;

  for (int rp = wid; rp < (M >> 1); rp += nw) {
    const size_t r0 = (size_t)rp << 1;
    float4 hv0[4], hv1[4];
#pragma unroll
    for (int j = 0; j < 4; ++j) {
      hv0[j] = h4[r0 * 256 + j * 64 + lane];
      hv1[j] = h4[(r0 + 1) * 256 + j * 64 + lane];
    }
    float d0[NPAT], d1[NPAT];
#pragma unroll
    for (int p = 0; p < NPAT; ++p) {
      float a = 0.f, b = 0.f;
#pragma unroll
      for (int j = 0; j < 4; ++j) {
        float4 pv = pl4[p * 256 + j * 64 + lane];
        a = fmaf(hv0[j].x, pv.x, a); a = fmaf(hv0[j].y, pv.y, a);
        a = fmaf(hv0[j].z, pv.z, a); a = fmaf(hv0[j].w, pv.w, a);
        b = fmaf(hv1[j].x, pv.x, b); b = fmaf(hv1[j].y, pv.y, b);
        b = fmaf(hv1[j].z, pv.z, b); b = fmaf(hv1[j].w, pv.w, b);
      }
      d0[p] = a; d1[p] = b;
    }
#pragma unroll
    for (int p = 0; p < NPAT; ++p) {
#pragma unroll
      for (int o = 32; o > 0; o >>= 1) {
        d0[p] += __shfl_xor(d0[p], o);
        d1[p] += __shfl_xor(d1[p], o);
      }
    }
    float m0 = d0[0], m1 = d1[0];
#pragma unroll
    for (int p = 1; p < NPAT; ++p) { m0 = fmaxf(m0, d0[p]); m1 = fmaxf(m1, d1[p]); }
    float s0 = 0.f, s1 = 0.f;
#pragma unroll
    for (int p = 0; p < NPAT; ++p) {
      d0[p] = __expf(d0[p] - m0); s0 += d0[p];
      d1[p] = __expf(d1[p] - m1); s1 += d1[p];
    }
    const float i0 = 1.f / s0, i1 = 1.f / s1;
#pragma unroll
    for (int p = 0; p < NPAT; ++p) { d0[p] *= i0; d1[p] *= i1; }

#pragma unroll
    for (int j = 0; j < 4; ++j) {
      float4 a0 = hv0[j], a1 = hv1[j];
#pragma unroll
      for (int p = 0; p < NPAT; ++p) {
        float4 pv = pl4[p * 256 + j * 64 + lane];
        a0.x = fmaf(d0[p], pv.x, a0.x); a0.y = fmaf(d0[p], pv.y, a0.y);
        a0.z = fmaf(d0[p], pv.z, a0.z); a0.w = fmaf(d0[p], pv.w, a0.w);
        a1.x = fmaf(d1[p], pv.x, a1.x); a1.y = fmaf(d1[p], pv.y, a1.y);
        a1.z = fmaf(d1[p], pv.z, a1.z); a1.w = fmaf(d1[p], pv.w, a1.w);
      }
      ushort4 o0, o1;
      o0.x = f2bf(a0.x); o0.y = f2bf(a0.y); o0.z = f2bf(a0.z); o0.w = f2bf(a0.w);
      o1.x = f2bf(a1.x); o1.y = f2bf(a1.y); o1.z = f2bf(a1.z); o1.w = f2bf(a1.w);
      A4[r0 * 256 + j * 64 + lane] = o0;
      A4[(r0 + 1) * 256 + j * 64 + lane] = o1;
    }
  }
}

// ---------------- K2: 256x256 8-phase bf16 GEMM (T2+T3+T4+T5) ----------------
// C[M,1024] = A_bf16 @ Wb^T + bias, f32 out.
// 512 thr = 8 waves (2M x 4N); per-wave out 128x64; BK=64; LDS 128 KiB.
// Schedule (phases per K-tile t; 2 barriers/phase; halves: Alo/Ahi/Blo/Bhi):
//   ph0: rd A m0-3 + B n0-1 ; stage Bhi_{t+1} ; MFMA q(0,0)
//   ph1: rd B n2-3          ; stage Ahi_{t+1} ; MFMA q(0,1)
//   ph2: rd A m4-7          ; stage Blo_{t+2} ; MFMA q(1,0)   [B-lo regions free after ph1]
//   ph3:                    ; stage Alo_{t+2} ; MFMA q(1,1)   [A regions free after ph2]
//        then vmcnt(4) (t+2<NKT) / vmcnt(0) (drain) — guarantees tile t+1 landed
//        while leaving the 2 newest halves (t+2's, 2 loads each) in flight.
// Write/read hazards all separated by >=2 barriered phases (see derivation).
// Swizzle: byte ^= ((row&7)<<4) — involution, 16B-chunk-preserving; applied to
// gload_lds SOURCE addresses (linear LDS dest) and to ds_read offsets.
#define STAGE(matBase, regionOff, kt, hf, bufOff)                                        \
  do {                                                                                   \
    const u16* _s = (matBase) + (size_t)((hf)*128) * DM + (kt)*64;                       \
    char* _d = lds + (regionOff) + (bufOff) + (hf)*16384;                                \
    __builtin_amdgcn_global_load_lds((gas_ptr)(_s + go0), (las_ptr)(_d + L0), 16, 0, 0); \
    __builtin_amdgcn_global_load_lds((gas_ptr)(_s + go1), (las_ptr)(_d + L1), 16, 0, 0); \
  } while (0)

#define RD(p) (*(const bf16x8_t*)(p))

__global__ __launch_bounds__(512, 2) void k2_gemm(const u16* __restrict__ A,
                                                  const u16* __restrict__ B,
                                                  const float* __restrict__ bias,
                                                  float* __restrict__ C, int M) {
  __shared__ __align__(16) char lds[131072];
  const int tid = threadIdx.x;
  const int lane = tid & 63;
  const int wave = tid >> 6;   // 0..7
  const int wm = wave >> 2;    // 0..1 -> A half
  const int wn = wave & 3;     // 0..3 -> B rows wn*64..+63
  const int r16 = lane & 15, kg = lane >> 4;

  // XCD-bijective swizzle: 1024 blocks % 8 == 0; 4 consecutive intra-XCD ids
  // share one A panel (tm) -> panel fetched ~once per XCD L2.
  const int bid = blockIdx.x;
  const int swz = (bid & 7) * 128 + (bid >> 3);
  const int tn = swz & 3, tm = swz >> 2;

  const u16* Ab = A + (size_t)tm * 256 * DM;
  const u16* Bb = B + (size_t)tn * 256 * DM;

  // staging thread->source map (inverse of read swizzle; involution)
  const uint32_t L0 = (uint32_t)tid * 16;
  const uint32_t L1 = 8192u + (uint32_t)tid * 16;
  const uint32_t S0 = L0 ^ (((L0 >> 7) & 7u) << 4);
  const uint32_t S1 = L1 ^ (((L1 >> 7) & 7u) << 4);
  const uint32_t go0 = (S0 >> 7) * DM + ((S0 & 127u) >> 1);
  const uint32_t go1 = (S1 >> 7) * DM + ((S1 & 127u) >> 1);

  // ds_read swizzled offsets (row&7 == r16&7 for both A and B patterns)
  const uint32_t flip = (uint32_t)(r16 & 7) << 4;
  const uint32_t aoff0 = ((uint32_t)(r16 * 128 + kg * 16)) ^ flip;         // ks=0
  const uint32_t aoff1 = ((uint32_t)(r16 * 128 + 64 + kg * 16)) ^ flip;    // ks=1
  const uint32_t brow = (uint32_t)((wn & 1) * 64 + r16);
  const uint32_t boff0 = ((uint32_t)(brow * 128 + kg * 16)) ^ flip;
  const uint32_t boff1 = ((uint32_t)(brow * 128 + 64 + kg * 16)) ^ flip;
  const uint32_t aHalfSel = (uint32_t)wm * 16384;
  const uint32_t bHalfSel = (uint32_t)(wn >> 1) * 16384;

  f32x4_t acc[8][4] = {};
  bf16x8_t aq[4][2], bl[2][2], bh[2][2];

  // prologue: flat stage order Blo0,Alo0,Bhi0,Ahi0,Blo1,Alo1 (12 vm instr/wave)
  STAGE(Bb, LDS_B, 0, 0, 0);
  STAGE(Ab, LDS_A, 0, 0, 0);
  STAGE(Bb, LDS_B, 0, 1, 0);
  STAGE(Ab, LDS_A, 0, 1, 0);
  STAGE(Bb, LDS_B, 1, 0, 32768);
  STAGE(Ab, LDS_A, 1, 0, 32768);
  asm volatile("s_waitcnt vmcnt(4)");  // tile0 landed; Blo1/Alo1 in flight
  __builtin_amdgcn_s_barrier();

  for (int t = 0; t < NKT; ++t) {
    const uint32_t co = (uint32_t)(t & 1) << 15;  // current buf byte offset
    const uint32_t no = co ^ 32768u;              // next buf
    const char* a0 = lds + LDS_A + co + aHalfSel + aoff0;
    const char* a1 = lds + LDS_A + co + aHalfSel + aoff1;
    const char* b0 = lds + LDS_B + co + bHalfSel + boff0;
    const char* b1 = lds + LDS_B + co + bHalfSel + boff1;

    // ---- phase 0: A m0-3, B n0-1 -> acc[0..3][0..1] ----
#pragma unroll
    for (int m = 0; m < 4; ++m) { aq[m][0] = RD(a0 + m * 2048); aq[m][1] = RD(a1 + m * 2048); }
#pragma unroll
    for (int n = 0; n < 2; ++n) { bl[n][0] = RD(b0 + n * 2048); bl[n][1] = RD(b1 + n * 2048); }
    if (t + 1 < NKT) STAGE(Bb, LDS_B, t + 1, 1, no);
    __builtin_amdgcn_s_barrier();
    asm volatile("s_waitcnt lgkmcnt(0)");
    __builtin_amdgcn_s_setprio(1);
#pragma unroll
    for (int m = 0; m < 4; ++m)
#pragma unroll
      for (int n = 0; n < 2; ++n)
#pragma unroll
        for (int ks = 0; ks < 2; ++ks)
          acc[m][n] = __builtin_amdgcn_mfma_f32_16x16x32_bf16(aq[m][ks], bl[n][ks], acc[m][n], 0, 0, 0);
    __builtin_amdgcn_s_setprio(0);
    __builtin_amdgcn_s_barrier();

    // ---- phase 1: B n2-3 -> acc[0..3][2..3] ----
#pragma unroll
    for (int n = 0; n < 2; ++n) { bh[n][0] = RD(b0 + (n + 2) * 2048); bh[n][1] = RD(b1 + (n + 2) * 2048); }
    if (t + 1 < NKT) STAGE(Ab, LDS_A, t + 1, 1, no);
    __builtin_amdgcn_s_barrier();
    asm volatile("s_waitcnt lgkmcnt(0)");
    __builtin_amdgcn_s_setprio(1);
#pragma unroll
    for (int m = 0; m < 4; ++m)
#pragma unroll
      for (int n = 0; n < 2; ++n)
#pragma unroll
        for (int ks = 0; ks < 2; ++ks)
          acc[m][n + 2] = __builtin_amdgcn_mfma_f32_16x16x32_bf16(aq[m][ks], bh[n][ks], acc[m][n + 2], 0, 0, 0);
    __builtin_amdgcn_s_setprio(0);
    __builtin_amdgcn_s_barrier();

    // ---- phase 2: A m4-7 -> acc[4..7][0..1] ----
#pragma unroll
    for (int m = 0; m < 4; ++m) { aq[m][0] = RD(a0 + (m + 4) * 2048); aq[m][1] = RD(a1 + (m + 4) * 2048); }
    if (t + 2 < NKT) STAGE(Bb, LDS_B, t + 2, 0, co);
    __builtin_amdgcn_s_barrier();
    asm volatile("s_waitcnt lgkmcnt(0)");
    __builtin_amdgcn_s_setprio(1);
#pragma unroll
    for (int m = 0; m < 4; ++m)
#pragma unroll
      for (int n = 0; n < 2; ++n)
#pragma unroll
        for (int ks = 0; ks < 2; ++ks)
          acc[m + 4][n] = __builtin_amdgcn_mfma_f32_16x16x32_bf16(aq[m][ks], bl[n][ks], acc[m + 4][n], 0, 0, 0);
    __builtin_amdgcn_s_setprio(0);
    __builtin_amdgcn_s_barrier();

    // ---- phase 3: -> acc[4..7][2..3] ; tile-end counted wait ----
    if (t + 2 < NKT) STAGE(Ab, LDS_A, t + 2, 0, co);
    __builtin_amdgcn_s_barrier();
    __builtin_amdgcn_s_setprio(1);
#pragma unroll
    for (int m = 0; m < 4; ++m)
#pragma unroll
      for (int n = 0; n < 2; ++n)
#pragma unroll
        for (int ks = 0; ks < 2; ++ks)
          acc[m + 4][n + 2] = __builtin_amdgcn_mfma_f32_16x16x32_bf16(aq[m][ks], bh[n][ks], acc[m + 4][n + 2], 0, 0, 0);
    __builtin_amdgcn_s_setprio(0);
    if (t < NKT - 1) {
      if (t + 2 < NKT) asm volatile("s_waitcnt vmcnt(4)");
      else             asm volatile("s_waitcnt vmcnt(0)");
    }
    __builtin_amdgcn_s_barrier();
  }

  // epilogue: C/D layout col=lane&15, row=(lane>>4)*4+reg
  const int colB = tn * 256 + wn * 64 + r16;
  const int rowB = tm * 256 + wm * 128 + kg * 4;
  float bvv[4];
#pragma unroll
  for (int n = 0; n < 4; ++n) bvv[n] = bias[colB + n * 16];
#pragma unroll
  for (int m = 0; m < 8; ++m) {
#pragma unroll
    for (int r = 0; r < 4; ++r) {
      float* cp = C + (size_t)(rowB + m * 16 + r) * DM + colB;
#pragma unroll
      for (int n = 0; n < 4; ++n) cp[n * 16] = acc[m][n][r] + bvv[n];
    }
  }
}

extern "C" void kernel_launch(void* const* d_in, const int* in_sizes, int n_in,
                              void* d_out, int out_size, void* d_ws, size_t ws_size,
                              hipStream_t stream) {
  const float* h = (const float*)d_in[0];
  const float* pat = (const float*)d_in[1];
  const float* w = (const float*)d_in[2];
  const float* b = (const float*)d_in[3];
  float* out = (float*)d_out;
  const int M = in_sizes[0] / DM;  // 65536

  u16* Wb = (u16*)d_ws;                     // 2 MiB
  u16* Abf = (u16*)d_ws + (size_t)DM * DM;  // 128 MiB

  k0_cvt_w<<<DM * DM / 4 / 256, 256, 0, stream>>>(w, Wb);
  k1_hopfield<<<2048, 256, 0, stream>>>(h, pat, Abf, M);
  k2_gemm<<<(M / 256) * (DM / 256), 512, 0, stream>>>(Abf, Wb, b, out, M);
}